// Round 7
// baseline (1092.677 us; speedup 1.0000x reference)
//
#include <hip/hip_runtime.h>

#define C_CH   64
#define H_IN   200
#define W_IN   320
#define H_OUT  48
#define W_OUT  320
#define N_BOX  256

typedef float float4v __attribute__((ext_vector_type(4), aligned(16)));

// R0 (measured best: 1053 us, kernel-only ~408 us) with EXACTLY ONE change:
// plain stores instead of __builtin_nontemporal_store. Single-variable test
// of the nt flag in the channel-fastest regime.
//
// Rationale: the harness's fillBufferAligned writes 4.03 GB at 6.2 TB/s with
// PLAIN stores (L2 write-allocate + full-line streamback) in these same
// sessions, while every nt-store variant of this kernel sustains only ~2.4
// TB/s effective. nt = no-allocate/stream path, the one store-path variable
// never isolated in this regime (R2 vs R3's nt-vs-wide null was in the
// box-fastest regime, where write-locality walls the kernel ~15% higher).
//
// Everything else is R0 verbatim: one block per (channel-fastest, box) pair,
// 320 threads; phase 1 stages 48 full-width rows via reg-staged dwordx4
// (3840 float4s / 320 thr = 12 each); phase 2: thread t = output column j,
// 48 conflict-free scalar LDS reads (lane col-step <= 1), coalesced stores.
__global__ __launch_bounds__(320, 2) void roi_crop_kernel(
    const float* __restrict__ x,
    const int*   __restrict__ bboxes,
    const int*   __restrict__ box_img,
    float*       __restrict__ out)
{
    __shared__ float tile[H_OUT * W_OUT];   // 48*320*4 = 61440 B

    const int c   = blockIdx.x;   // channel 0..63
    const int box = blockIdx.y;   // box     0..255
    const int t   = threadIdx.x;  // 0..319

    int x0 = bboxes[box * 4 + 0];
    int y0 = bboxes[box * 4 + 1];
    int x1 = bboxes[box * 4 + 2];
    int y1 = bboxes[box * 4 + 3];

    x0 = min(max(x0, 0), W_IN - 1);
    y0 = min(max(y0, 0), H_IN - 1);
    x1 = min(max(x1, 0), W_IN - 1);
    y1 = min(max(y1, 0), H_IN - 1);
    x1 = max(x1, x0);
    y1 = max(y1, y0);

    const int h = y1 - y0 + 1;
    const int w = x1 - x0 + 1;
    const int img = box_img[box];

    const float* __restrict__ plane_in =
        x + ((size_t)img * C_CH + c) * (H_IN * W_IN);
    float* __restrict__ plane_out =
        out + ((size_t)box * C_CH + c) * (H_OUT * W_OUT);

    // ---- Phase 1: stage 48 rows x 320 cols. 3840 float4s / 320 threads = 12 each.
    float4v v[12];
    #pragma unroll
    for (int k = 0; k < 12; ++k) {
        const int p   = t + k * 320;      // float4 index 0..3839
        const int i   = p / 80;           // output row (80 float4 per row)
        const int wrd = p % 80;           // float4 within row
        const int r   = y0 + (i * h) / H_OUT;
        v[k] = *(const float4v*)(plane_in + (size_t)r * W_IN + wrd * 4);
    }
    #pragma unroll
    for (int k = 0; k < 12; ++k) {
        const int p = t + k * 320;
        *(float4v*)&tile[p * 4] = v[k];
    }
    __syncthreads();

    // ---- Phase 2: gather + contiguous PLAIN store. j = t.
    const int col = x0 + (t * w) / W_OUT;  // adjacent lanes: col step <= 1 → conflict-free
    #pragma unroll 8
    for (int i = 0; i < H_OUT; ++i) {
        const float val = tile[i * W_OUT + col];
        plane_out[i * W_OUT + t] = val;    // plain store: L2 write-allocate path
    }
}

extern "C" void kernel_launch(void* const* d_in, const int* in_sizes, int n_in,
                              void* d_out, int out_size, void* d_ws, size_t ws_size,
                              hipStream_t stream) {
    const float* x       = (const float*)d_in[0];
    const int*   bboxes  = (const int*)d_in[1];
    const int*   box_img = (const int*)d_in[2];
    float*       out     = (float*)d_out;

    dim3 grid(C_CH, N_BOX);   // (64, 256) = 16384 blocks
    dim3 block(320);
    roi_crop_kernel<<<grid, block, 0, stream>>>(x, bboxes, box_img, out);
}

// Round 9
// 1081.657 us; speedup vs baseline: 1.0102x; 1.0102x over previous
//
#include <hip/hip_runtime.h>

#define C_CH   64
#define H_IN   200
#define W_IN   320
#define H_OUT  48
#define W_OUT  320
#define N_BOX  256

typedef float float4v __attribute__((ext_vector_type(4), aligned(16)));

// R0 (measured best: 1053 us; nt > plain confirmed by R7 A/B: +40 us) with
// EXACTLY ONE change: T1 XCD-chunked blockIdx swizzle.
// (Resubmission of round 8 — previous bench aborted on a container
// infrastructure failure before compile/run; no kernel-side evidence.)
//
// Default dispatch round-robins blocks over 8 XCDs -> XCD k gets channels
// c == k (mod 8) of every box: its write stream is 61 KB fragments at 492 KB
// stride. With swz = (raw&7)*2048 + raw>>3 (bijective: 16384 % 8 == 0), each
// XCD owns one contiguous span of 2048 logical tiles = 32 complete boxes ->
// one contiguous 126 MB output region per XCD L2, and a read set of ~4
// images' planes with cross-box row reuse. Grid order was the only lever
// that ever moved this kernel (~50 us, R0 vs R1-R3), so dispatch->locality
// mapping is demonstrably live.
//
// Everything else is R0 verbatim: one block per (channel, box), 320 threads;
// phase 1 stages 48 full-width rows via reg-staged dwordx4 (12/thread);
// phase 2: thread t = output column j, 48 conflict-free scalar LDS reads
// (lane col-step <= 1), contiguous nontemporal dword stores.
__global__ __launch_bounds__(320, 2) void roi_crop_kernel(
    const float* __restrict__ x,
    const int*   __restrict__ bboxes,
    const int*   __restrict__ box_img,
    float*       __restrict__ out)
{
    __shared__ float tile[H_OUT * W_OUT];   // 48*320*4 = 61440 B

    const int raw = blockIdx.x;                      // 0..16383
    const int swz = (raw & 7) * 2048 + (raw >> 3);   // XCD-chunked bijection
    const int c   = swz & 63;                        // channel 0..63 (fastest)
    const int box = swz >> 6;                        // box 0..255
    const int t   = threadIdx.x;                     // 0..319

    int x0 = bboxes[box * 4 + 0];
    int y0 = bboxes[box * 4 + 1];
    int x1 = bboxes[box * 4 + 2];
    int y1 = bboxes[box * 4 + 3];

    x0 = min(max(x0, 0), W_IN - 1);
    y0 = min(max(y0, 0), H_IN - 1);
    x1 = min(max(x1, 0), W_IN - 1);
    y1 = min(max(y1, 0), H_IN - 1);
    x1 = max(x1, x0);
    y1 = max(y1, y0);

    const int h = y1 - y0 + 1;
    const int w = x1 - x0 + 1;
    const int img = box_img[box];

    const float* __restrict__ plane_in =
        x + ((size_t)img * C_CH + c) * (H_IN * W_IN);
    float* __restrict__ plane_out =
        out + ((size_t)box * C_CH + c) * (H_OUT * W_OUT);

    // ---- Phase 1: stage 48 rows x 320 cols. 3840 float4s / 320 threads = 12 each.
    float4v v[12];
    #pragma unroll
    for (int k = 0; k < 12; ++k) {
        const int p   = t + k * 320;      // float4 index 0..3839
        const int i   = p / 80;           // output row (80 float4 per row)
        const int wrd = p % 80;           // float4 within row
        const int r   = y0 + (i * h) / H_OUT;
        v[k] = *(const float4v*)(plane_in + (size_t)r * W_IN + wrd * 4);
    }
    #pragma unroll
    for (int k = 0; k < 12; ++k) {
        const int p = t + k * 320;
        *(float4v*)&tile[p * 4] = v[k];
    }
    __syncthreads();

    // ---- Phase 2: gather + contiguous nt store. j = t.
    const int col = x0 + (t * w) / W_OUT;  // adjacent lanes: col step <= 1 → conflict-free
    #pragma unroll 8
    for (int i = 0; i < H_OUT; ++i) {
        const float val = tile[i * W_OUT + col];
        __builtin_nontemporal_store(val, plane_out + i * W_OUT + t);
    }
}

extern "C" void kernel_launch(void* const* d_in, const int* in_sizes, int n_in,
                              void* d_out, int out_size, void* d_ws, size_t ws_size,
                              hipStream_t stream) {
    const float* x       = (const float*)d_in[0];
    const int*   bboxes  = (const int*)d_in[1];
    const int*   box_img = (const int*)d_in[2];
    float*       out     = (float*)d_out;

    dim3 grid(C_CH * N_BOX);   // 16384 blocks, 1-D (swizzled in-kernel)
    dim3 block(320);
    roi_crop_kernel<<<grid, block, 0, stream>>>(x, bboxes, box_img, out);
}